// Round 2
// baseline (51.221 us; speedup 1.0000x reference)
//
#include <hip/hip_runtime.h>
#include <hip/hip_bf16.h>

#define BATCH 8192
#define DDIM 512
#define FDIM 64
#define KD 64

typedef __attribute__((ext_vector_type(8))) short short8;
typedef __attribute__((ext_vector_type(4))) float f32x4;

static __device__ __forceinline__ unsigned short f2bf(float f) {
    __hip_bfloat16 h = __float2bfloat16(f);
    return *reinterpret_cast<unsigned short*>(&h);
}

// ---------------- W^T (bf16, N-major) + zero out ----------------
// WT[j*D + i] = (i<j) ? dot(kernel[i,fd[j],:], kernel[j,fd[i],:]) : 0
__global__ void w_kernel(const float* __restrict__ kern, const int* __restrict__ fd,
                         unsigned short* __restrict__ WT, float* __restrict__ out) {
    const int j = blockIdx.y;
    const int i = blockIdx.x * 256 + threadIdx.x;
    // fold out-zeroing into this kernel (runs before quad on the stream)
    if (blockIdx.x == 0 && j < BATCH / 256) out[j * 256 + threadIdx.x] = 0.f;
    float v = 0.f;
    if (i < j) {
        const float* a = kern + ((size_t)i * FDIM + fd[j]) * KD;
        const float* b = kern + ((size_t)j * FDIM + fd[i]) * KD;
#pragma unroll
        for (int k = 0; k < KD; k += 4) {
            float4 av = *reinterpret_cast<const float4*>(a + k);
            float4 bv = *reinterpret_cast<const float4*>(b + k);
            v += av.x * bv.x + av.y * bv.y + av.z * bv.z + av.w * bv.w;
        }
    }
    WT[(size_t)j * DDIM + i] = f2bf(v);
}

// ---------------- fused  out[b] += x[b,:] @ Wm @ x[b,:]  (MFMA bf16) ----------------
#define BM 64
#define BN 128
#define BK 64
#define NITER (DDIM / BK)

__global__ __launch_bounds__(256) void quad_kernel(const float* __restrict__ x,
                                                   const unsigned short* __restrict__ WT,
                                                   float* __restrict__ out) {
    __shared__ unsigned short As[BM * BK];   // [row][k], 16B-chunk XOR-swizzled (8 chunks/row)
    __shared__ unsigned short Bs[BN * BK];

    const int tid = threadIdx.x;
    const int lane = tid & 63;
    const int w = tid >> 6;          // wave 0..3
    const int wm = w >> 1, wn = w & 1;
    const int ln = lane & 15, l4 = lane >> 4;
    const int mbase = blockIdx.x * BM;
    const int nbase = blockIdx.y * BN;

    f32x4 acc[2][4] = {};

    const int arow = tid >> 2;       // 0..63, A row
    const int ac = tid & 3;          // 16-float chunk within row
    const int brow = tid >> 2;       // B rows brow, brow+64
    const int bc = tid & 3;

    float4 areg[4];
    int4 breg[4];

    auto loadA = [&](int kk) {
        const float4* src = reinterpret_cast<const float4*>(x + (size_t)(mbase + arow) * DDIM + kk + ac * 16);
#pragma unroll
        for (int u = 0; u < 4; ++u) areg[u] = src[u];
    };
    auto loadB = [&](int kk) {
#pragma unroll
        for (int r = 0; r < 2; ++r) {
            const int4* src = reinterpret_cast<const int4*>(WT + (size_t)(nbase + brow + r * 64) * DDIM + kk);
#pragma unroll
            for (int u = 0; u < 2; ++u) breg[r * 2 + u] = src[bc * 2 + u];
        }
    };
    auto writeA = [&]() {
#pragma unroll
        for (int h = 0; h < 2; ++h) {
            float4 p = areg[2 * h], q = areg[2 * h + 1];
            short8 v;
            v[0] = (short)f2bf(p.x); v[1] = (short)f2bf(p.y);
            v[2] = (short)f2bf(p.z); v[3] = (short)f2bf(p.w);
            v[4] = (short)f2bf(q.x); v[5] = (short)f2bf(q.y);
            v[6] = (short)f2bf(q.z); v[7] = (short)f2bf(q.w);
            int chunk = (2 * ac + h) ^ (arow & 7);
            *reinterpret_cast<short8*>(As + arow * BK + chunk * 8) = v;
        }
    };
    auto writeB = [&]() {
#pragma unroll
        for (int r = 0; r < 2; ++r)
#pragma unroll
            for (int u = 0; u < 2; ++u) {
                int row = brow + r * 64;
                int chunk = (2 * bc + u) ^ (row & 7);
                *reinterpret_cast<int4*>(Bs + row * BK + chunk * 8) = breg[r * 2 + u];
            }
    };

    loadA(0); loadB(0);
    writeA(); writeB();
    __syncthreads();

    for (int t = 0; t < NITER; ++t) {
        const bool more = (t + 1 < NITER);
        if (more) { loadA((t + 1) * BK); loadB((t + 1) * BK); }   // issue early, hide under compute

        short8 a[2][2], b[2][4];
#pragma unroll
        for (int ks = 0; ks < 2; ++ks) {
#pragma unroll
            for (int m = 0; m < 2; ++m) {
                int row = wm * 32 + m * 16 + ln;
                int chunk = (ks * 4 + l4) ^ (row & 7);
                a[ks][m] = *reinterpret_cast<const short8*>(As + row * BK + chunk * 8);
            }
#pragma unroll
            for (int n = 0; n < 4; ++n) {
                int col = wn * 64 + n * 16 + ln;
                int chunk = (ks * 4 + l4) ^ (col & 7);
                b[ks][n] = *reinterpret_cast<const short8*>(Bs + col * BK + chunk * 8);
            }
        }
#pragma unroll
        for (int ks = 0; ks < 2; ++ks)
#pragma unroll
            for (int m = 0; m < 2; ++m)
#pragma unroll
                for (int n = 0; n < 4; ++n)
                    acc[m][n] = __builtin_amdgcn_mfma_f32_16x16x32_bf16(a[ks][m], b[ks][n], acc[m][n], 0, 0, 0);

        __syncthreads();                   // frag reads of tile t done
        if (more) { writeA(); writeB(); __syncthreads(); }
    }

    // epilogue: out[row] += sum_col y[row][col] * x[row][col]
#pragma unroll
    for (int m = 0; m < 2; ++m) {
#pragma unroll
        for (int q = 0; q < 4; ++q) {
            int grow = mbase + wm * 32 + m * 16 + l4 * 4 + q;   // C/D: row=(lane>>4)*4+reg
            float s = 0.f;
#pragma unroll
            for (int n = 0; n < 4; ++n) {
                int gcol = nbase + wn * 64 + n * 16 + ln;        // C/D: col=lane&15
                s += acc[m][n][q] * x[(size_t)grow * DDIM + gcol];
            }
#pragma unroll
            for (int off = 1; off < 16; off <<= 1)
                s += __shfl_xor(s, off, 64);
            if (ln == 0) atomicAdd(out + grow, s);
        }
    }
}

extern "C" void kernel_launch(void* const* d_in, const int* in_sizes, int n_in,
                              void* d_out, int out_size, void* d_ws, size_t ws_size,
                              hipStream_t stream) {
    const float* x = (const float*)d_in[0];
    const float* kern = (const float*)d_in[1];
    const int* fd = (const int*)d_in[2];
    float* out = (float*)d_out;

    unsigned short* WT = (unsigned short*)d_ws;

    dim3 wgrid(2, DDIM);
    w_kernel<<<wgrid, 256, 0, stream>>>(kern, fd, WT, out);
    dim3 qgrid(BATCH / BM, DDIM / BN);
    quad_kernel<<<qgrid, 256, 0, stream>>>(x, WT, out);
}